// Round 10
// baseline (181.436 us; speedup 1.0000x reference)
//
#include <hip/hip_runtime.h>

// Problem constants (fixed by the harness / reference setup_inputs)
#define B_ 2
#define K_ 33
#define N_ 50000
#define E_ 800000
#define R_ 200
#define D_ 64
#define L_ 3

#define ROWCAP 95000      // rowlist entries
#define NV4 200000        // E/4 int4-groups
#define SCAT_BLOCKS 391   // fallback scan grid
#define SCAT_THREADS (SCAT_BLOCKS * 256)
#define FGRID 256         // fused grid: 1 block/CU, co-resident via cooperative launch
#define FTHREADS (FGRID * 256)
#define NGRP 16           // barrier tree: 16 groups x 16 blocks
#define GSZ  16
#define READY_MAGIC 0x5F0F00D5CAFEB007ull
#define ECAP_LDS 4000     // edge records staged in LDS (32 KB); global fallback above
#define ZCHUNK 196        // ceil(50,000 flags-u64 / 256)

#define SCOPE_AG __HIP_MEMORY_SCOPE_AGENT

// ---- relaxed agent-scope (cross-XCD coherent, no cache-wide fences) ----
// R4-R9 lessons: ockl grid.sync ~45us/barrier; tree barrier ~3us; body
// cost = serialized coherence round trips (R8) + uncached-store traffic
// (R9: WRITE_SIZE 26MB == the agg zero ~= 25us). This round deletes agg
// entirely: scatter communicates via a compact active-edge list (~600
// records/layer), update gathers per-row from it. P0 zeroes only flags.
__device__ inline float aldf(float* p)            { return __hip_atomic_load(p, __ATOMIC_RELAXED, SCOPE_AG); }
__device__ inline void  astf(float* p, float v)   { __hip_atomic_store(p, v, __ATOMIC_RELAXED, SCOPE_AG); }
__device__ inline int   aldi(int* p)              { return __hip_atomic_load(p, __ATOMIC_RELAXED, SCOPE_AG); }
__device__ inline void  asti(int* p, int v)       { __hip_atomic_store(p, v, __ATOMIC_RELAXED, SCOPE_AG); }
__device__ inline unsigned aldu(unsigned* p)      { return __hip_atomic_load(p, __ATOMIC_RELAXED, SCOPE_AG); }
__device__ inline void  astu(unsigned* p, unsigned v) { __hip_atomic_store(p, v, __ATOMIC_RELAXED, SCOPE_AG); }
__device__ inline unsigned long long ald64(unsigned long long* p) { return __hip_atomic_load(p, __ATOMIC_RELAXED, SCOPE_AG); }
__device__ inline void  ast64(unsigned long long* p, unsigned long long v) { __hip_atomic_store(p, v, __ATOMIC_RELAXED, SCOPE_AG); }

// Two-level tree barrier, monotonic epochs (no reset races). See R6.
__device__ inline void gridbar(unsigned* bar, unsigned epoch) {
    __syncthreads();    // per-wave vmcnt(0) drain before s_barrier = release
    if (threadIdx.x == 0) {
        const int g = (int)(blockIdx.x >> 4);
        unsigned* gcnt = bar + (1 + g) * 32;
        unsigned* ggo  = gcnt + 1;
        unsigned prev = __hip_atomic_fetch_add(gcnt, 1u, __ATOMIC_RELAXED, SCOPE_AG);
        if (prev == epoch * GSZ - 1) {              // last arriver in group
            unsigned r = __hip_atomic_fetch_add(bar, 1u, __ATOMIC_RELAXED, SCOPE_AG);
            if (r == epoch * NGRP - 1) {            // last group -> release everyone
                #pragma unroll
                for (int i = 0; i < NGRP; ++i)
                    astu(bar + (1 + i) * 32 + 1, epoch);
            }
        }
        while (aldu(ggo) < epoch) __builtin_amdgcn_s_sleep(1);
    }
    __syncthreads();
}

__device__ inline float wave_sum64(float v) {
    for (int m = 32; m; m >>= 1) v += __shfl_xor(v, m, 64);
    return v;
}

// flags bits: 1 = x-active, 4 = rowlist claim.
// Workspace layout (proven ws_size >= 52,000,288):
//   x       @ 0           25,600,000  (reads gated by flags bit0)
//   elist   @ 25,600,000  25,600,000  (3.2M u64 records; cap >= E*B worst case)
//   flags   @ 51,200,000     400,000  (zeroed, balanced)
//   rowlist @ 51,600,000     380,000  (ROWCAP entries, ends 51,980,000)
//   ecnt[3] @ 51,980,016          12
//   bar     @ 51,980,032       2,176  (17 x 128 B tree-barrier lines)
//   ready   @ 51,987,480  (u64 magic)
//   rowcnt  @ 52,000,000  hb @ +8  rb @ +16  tb @ +24 (264 B)

struct FusedArgs {
    const float *rel, *layer_w, *layer_b, *ln_g, *ln_b;
    const float *mlp_w1, *mlp_b1, *mlp_w2, *mlp_b2;
    const int *raw, *ei, *etype;
    char* ws;
    float* out;
};

__global__ __launch_bounds__(256) void fused_kernel(FusedArgs A) {
    char* ws = A.ws;
    float*    x       = (float*)(ws);
    unsigned long long* elist = (unsigned long long*)(ws + 25600000);
    int*      flags   = (int*)(ws + 51200000);
    int*      rowlist = (int*)(ws + 51600000);
    int*      ecnt    = (int*)(ws + 51980016);
    unsigned* bar     = (unsigned*)(ws + 51980032);
    unsigned long long* ready = (unsigned long long*)(ws + 51987480);
    int*      rowcnt  = (int*)(ws + 52000000);
    int*      hb      = (int*)(ws + 52000008);
    int*      rb      = (int*)(ws + 52000016);
    int*      tb      = (int*)(ws + 52000024);
    unsigned long long* fzu = (unsigned long long*)flags;  // 50,000 u64

    const int tid  = threadIdx.x;
    const int lane = tid & 63;
    const int gtid = blockIdx.x * 256 + tid;
    const int gw   = gtid >> 6;                 // global wave id, 0..1023

    __shared__ unsigned long long bsll[1564];   // 12,512 B LDS src-activity bitset
    __shared__ unsigned long long tact[1564];   // 12,512 B target-dst bitset (L3 filter)
    __shared__ unsigned long long elds[ECAP_LDS]; // 32,000 B staged edge records
    __shared__ int tbl_s[B_ * K_];              // staged t-indices (66)
    __shared__ int nz_s, cnt_s, fc_s, ce_s;

    // ---- barrier bootstrap over poisoned ws (block0 publishes magic) ----
    if (blockIdx.x == 0) {
        for (int i = tid; i < 17 * 32; i += 256) astu(&bar[i], 0u);
        __syncthreads();                        // drains all zero-stores
        if (tid == 0) ast64(ready, READY_MAGIC);
    } else if (tid == 0) {
        while (ald64(ready) != READY_MAGIC) __builtin_amdgcn_s_sleep(1);
    }

    // ---------- P0: balanced flags zero + decode + x seed ----------
    {
        int lo = blockIdx.x * ZCHUNK;
        int hi = lo + ZCHUNK; if (hi > 50000) hi = 50000;
        for (int i = lo + tid; i < hi; i += 256) ast64(&fzu[i], 0ull);
    }
    if (blockIdx.x == 0) {
        if (tid == 0) {
            asti(rowcnt, 0);
            asti(&ecnt[0], 0); asti(&ecnt[1], 0); asti(&ecnt[2], 0);
            nz_s = 0;
        }
        __syncthreads();
        // int64-vs-int32 batch detect: any hi-word nonzero -> int32 (stride 1)
        if (tid < 99 && A.raw[2 * tid + 1] != 0) atomicOr(&nz_s, 1);
        __syncthreads();
        const int st = nz_s ? 1 : 2;
        for (int i = tid; i < B_ * K_; i += 256) asti(&tb[i], A.raw[(i * 3 + 1) * st]);
        if (tid < B_) {
            asti(&hb[tid], A.raw[(tid * K_ * 3 + 0) * st]);
            asti(&rb[tid], A.raw[(tid * K_ * 3 + 2) * st]);
        }
        __syncthreads();
        if (tid < 128) {                        // x seed only (flags deferred)
            int b = tid >> 6;
            int h = A.raw[(b * K_ * 3 + 0) * st];
            int r = A.raw[(b * K_ * 3 + 2) * st];
            astf(&x[(b * N_ + h) * D_ + lane], A.rel[(b * R_ + r) * D_ + lane]);
        }
    }
    unsigned bark = 0;
    gridbar(bar, ++bark);

    // hb/rb constant after P0 — hoist coherent reads once.
    const int hb0 = aldi(&hb[0]), hb1 = aldi(&hb[1]);
    const int rb0 = aldi(&rb[0]), rb1 = aldi(&rb[1]);

    // ---- stage tb into LDS + build per-block target-dst bitset (once) ----
    for (int i = tid; i < 1564; i += 256) tact[i] = 0ull;
    if (tid < B_ * K_) tbl_s[tid] = aldi(&tb[tid]);
    __syncthreads();
    if (tid < B_ * K_) {
        int b = tid / K_;
        int t = tbl_s[tid];
        atomicOr(&((unsigned*)tact)[t >> 4], 1u << (((t & 15) << 1) | b));
    }
    __syncthreads();

    // ---------- layers ----------
    for (int l = 0; l < L_; ++l) {
        const float* W    = A.layer_w + (size_t)l * 128 * 64;
        const float* bias = A.layer_b + l * 64;
        const float* gam  = A.ln_g + l * 64;
        const float* bet  = A.ln_b + l * 64;

        // ---- build LDS src-activity bitset from the frontier (R9 proven) ----
        for (int i = tid; i < 1564; i += 256) bsll[i] = 0ull;
        if (tid == 0 && l > 0) fc_s = min(aldi(rowcnt), ROWCAP);
        __syncthreads();
        {
            unsigned* bsw = (unsigned*)bsll;
            if (l == 0) {
                if (tid == 0) {
                    bsw[hb0 >> 4] |= 1u << (((hb0 & 15) << 1) | 0);
                    bsw[hb1 >> 4] |= 1u << (((hb1 & 15) << 1) | 1);
                }
            } else {
                int pairs = (fc_s + 1) >> 1;
                for (int i = tid; i < pairs; i += 256) {
                    unsigned long long v = ald64((unsigned long long*)&rowlist[2 * i]);
                    int r0 = (int)(unsigned)v;
                    int c0 = (r0 >= N_) ? 1 : 0, n0 = r0 - c0 * N_;
                    atomicOr(&bsw[n0 >> 4], 1u << (((n0 & 15) << 1) | c0));
                    if (2 * i + 1 < fc_s) {
                        int r1 = (int)(v >> 32);
                        int c1 = (r1 >= N_) ? 1 : 0, n1 = r1 - c1 * N_;
                        atomicOr(&bsw[n1 >> 4], 1u << (((n1 & 15) << 1) | c1));
                    }
                }
            }
        }
        __syncthreads();
        // Deferred seed claims (idempotent vs concurrent scan claims).
        if (l == 0 && blockIdx.x == 0 && tid < B_) {
            int row = tid * N_ + (tid ? hb1 : hb0);
            int old = atomicOr(&flags[row], 1 | 4);
            if (!(old & 4)) {
                int idx = atomicAdd(rowcnt, 1);
                if (idx < ROWCAP) asti(&rowlist[idx], row);
            }
        }

        // ---- scan: O(E) cached probe; actives -> packed edge-list append ----
        // No x reads, no dense accumulator. One wave-batched atomicAdd per
        // ballot group reserves slots; lanes store (di|si<<16|ti<<32|b<<40).
        // l==2: dst must also be in the target set; no claims.
        {
            const unsigned* bs = (const unsigned*)bsll;
            const unsigned* tw = (const unsigned*)tact;
            for (int i = gtid; i < NV4; i += FTHREADS) {
                int4 u = ((const int4*)A.ei)[i];        // ei read-only: plain cached
                int sv[4] = {u.x, u.y, u.z, u.w};
                int dv[4] = {0, 0, 0, 0};
                unsigned act = 0;
                #pragma unroll
                for (int k = 0; k < 4; ++k) {
                    int s = sv[k];
                    act |= ((bs[s >> 4] >> ((s & 15) << 1)) & 3u) << (k * 2);
                }
                if (l == 2) {                           // wave-uniform branch
                    int4 ud = ((const int4*)(A.ei + E_))[i];
                    dv[0] = ud.x; dv[1] = ud.y; dv[2] = ud.z; dv[3] = ud.w;
                    unsigned tm = 0;
                    #pragma unroll
                    for (int k = 0; k < 4; ++k) {
                        int d = dv[k];
                        tm |= ((tw[d >> 4] >> ((d & 15) << 1)) & 3u) << (k * 2);
                    }
                    act &= tm;
                }
                #pragma unroll
                for (int k = 0; k < 4; ++k) {
                    #pragma unroll
                    for (int b = 0; b < B_; ++b) {
                        bool mine = (act >> (k * 2 + b)) & 1;
                        unsigned long long mask = __ballot(mine);
                        if (!mask) continue;
                        int leader = __builtin_ctzll(mask);
                        int base = 0;
                        if (lane == leader)
                            base = atomicAdd(&ecnt[l], (int)__popcll(mask));
                        base = __shfl(base, leader, 64);
                        if (mine) {
                            int rank = (int)__popcll(mask & ((1ull << lane) - 1ull));
                            int e  = i * 4 + k;                 // own edge
                            int si = sv[k];
                            int di = (l == 2) ? dv[k] : A.ei[E_ + e];
                            int ti = A.etype[e];
                            unsigned long long rec =
                                (unsigned long long)(unsigned)di
                              | ((unsigned long long)(unsigned)si << 16)
                              | ((unsigned long long)(unsigned)ti << 32)
                              | ((unsigned long long)(unsigned)b  << 40);
                            ast64(&elist[base + rank], rec);
                            if (l < 2) {
                                int drow = b * N_ + di;
                                int old = atomicOr(&flags[drow], 4);
                                if (!(old & 4)) {
                                    int idx = atomicAdd(rowcnt, 1);
                                    if (idx < ROWCAP) asti(&rowlist[idx], drow);
                                }
                            }
                        }
                    }
                }
            }
        }
        gridbar(bar, ++bark);

        // ---- stage this layer's edge list (shared by both update paths) ----
        if (tid == 0) {
            ce_s = aldi(&ecnt[l]);
            cnt_s = min(aldi(rowcnt), ROWCAP);
        }
        __syncthreads();
        const int ce = ce_s;
        const bool inlds = (ce <= ECAP_LDS);
        if (inlds) for (int j = tid; j < ce; j += 256) elds[j] = ald64(&elist[j]);
        __syncthreads();

        if (l < 2) {
            // ---- update: gather from edge list; [a, x] @ W; LN; relu; x += ----
            const int cnt = cnt_s;
            for (int idx = gw; idx < cnt; idx += FTHREADS >> 6) {
                int row = aldi(&rowlist[idx]);
                int f = aldi(&flags[row]);
                int b = (row >= N_) ? 1 : 0;
                int node = row - b * N_;
                float a = 0.0f;
                for (int j0 = 0; j0 < ce; j0 += 64) {
                    int jj = j0 + lane;
                    unsigned long long rec = 0;
                    bool valid = jj < ce;
                    if (valid) rec = inlds ? elds[jj] : ald64(&elist[jj]);
                    bool match = valid && ((int)(rec & 0xFFFFu) == node)
                                       && ((int)((rec >> 40) & 1u) == b);
                    unsigned long long mask = __ballot(match);
                    while (mask) {
                        int j = __builtin_ctzll(mask);
                        mask &= mask - 1;
                        unsigned long long rj = __shfl(rec, j, 64);
                        int si = (int)((rj >> 16) & 0xFFFFu);
                        int ti = (int)((rj >> 32) & 0xFFu);
                        a += aldf(&x[(b * N_ + si) * D_ + lane])
                           * A.rel[(b * R_ + ti) * D_ + lane];
                    }
                }
                if (node == (b ? hb1 : hb0))            // boundary (= query)
                    a += A.rel[(b * R_ + (b ? rb1 : rb0)) * D_ + lane];
                float xo = (f & 1) ? aldf(&x[row * D_ + lane]) : 0.0f;
                float y = bias[lane];
                #pragma unroll 8
                for (int i = 0; i < 64; ++i)
                    y += __shfl(a, i, 64) * W[i * 64 + lane];
                #pragma unroll 8
                for (int i = 0; i < 64; ++i)
                    y += __shfl(xo, i, 64) * W[(64 + i) * 64 + lane];
                float mu = wave_sum64(y) * (1.0f / 64.0f);
                float dlt = y - mu;
                float var = wave_sum64(dlt * dlt) * (1.0f / 64.0f);
                float upd = fmaxf(dlt * rsqrtf(var + 1e-5f) * gam[lane] + bet[lane], 0.0f);
                astf(&x[row * D_ + lane], upd + xo);
                if (lane == 0)
                    asti(&flags[row], f | 1);           // x-active
            }
            gridbar(bar, ++bark);
        } else {
            // ---- L3 update + score fused, targets only, no barrier after ----
            if (gw < B_ * K_) {
                int b = gw / K_;
                int t = tbl_s[gw];
                int row = b * N_ + t;
                int f = aldi(&flags[row]);
                float a = 0.0f;
                for (int j0 = 0; j0 < ce; j0 += 64) {
                    int jj = j0 + lane;
                    unsigned long long rec = 0;
                    bool valid = jj < ce;
                    if (valid) rec = inlds ? elds[jj] : ald64(&elist[jj]);
                    bool match = valid && ((int)(rec & 0xFFFFu) == t)
                                       && ((int)((rec >> 40) & 1u) == b);
                    unsigned long long mask = __ballot(match);
                    while (mask) {
                        int j = __builtin_ctzll(mask);
                        mask &= mask - 1;
                        unsigned long long rj = __shfl(rec, j, 64);
                        int si = (int)((rj >> 16) & 0xFFFFu);
                        int ti = (int)((rj >> 32) & 0xFFu);
                        a += aldf(&x[(b * N_ + si) * D_ + lane])
                           * A.rel[(b * R_ + ti) * D_ + lane];
                    }
                }
                if (t == (b ? hb1 : hb0))               // boundary (= query)
                    a += A.rel[(b * R_ + (b ? rb1 : rb0)) * D_ + lane];
                float xo = (f & 1) ? aldf(&x[row * D_ + lane]) : 0.0f;
                float y = bias[lane];
                #pragma unroll 8
                for (int i = 0; i < 64; ++i)
                    y += __shfl(a, i, 64) * W[i * 64 + lane];
                #pragma unroll 8
                for (int i = 0; i < 64; ++i)
                    y += __shfl(xo, i, 64) * W[(64 + i) * 64 + lane];
                float mu = wave_sum64(y) * (1.0f / 64.0f);
                float dlt = y - mu;
                float var = wave_sum64(dlt * dlt) * (1.0f / 64.0f);
                float upd = fmaxf(dlt * rsqrtf(var + 1e-5f) * gam[lane] + bet[lane], 0.0f);
                float res = upd + xo;                   // x3[row], in-register
                // inline final MLP score
                float q = A.rel[(b * R_ + (b ? rb1 : rb0)) * D_ + lane];
                float acc = A.mlp_b1[lane];
                #pragma unroll 8
                for (int i = 0; i < 64; ++i)
                    acc += __shfl(res, i, 64) * A.mlp_w1[i * 64 + lane];
                #pragma unroll 8
                for (int i = 0; i < 64; ++i)
                    acc += __shfl(q, i, 64) * A.mlp_w1[(64 + i) * 64 + lane];
                acc = fmaxf(acc, 0.0f);
                float s = wave_sum64(acc * A.mlp_w2[lane]);
                if (lane == 0) A.out[gw] = s + A.mlp_b2[0];
            }
        }
    }

    // Reset magic so a future run never sees stale MAGIC with un-zeroed
    // counters (hang hazard if a poison pass is ever skipped).
    if (blockIdx.x == 0 && tid == 0) ast64(ready, 0ull);
}

// =====================================================================
// Fallback path: proven R1 multi-kernel pipeline (launch-error only)
// =====================================================================
__global__ void init_kernel(const int* __restrict__ raw,
                            int* __restrict__ hb, int* __restrict__ rb,
                            int* __restrict__ tb,
                            float* __restrict__ x, int* __restrict__ flags,
                            unsigned* __restrict__ bitset,
                            int* __restrict__ rowlist, int* __restrict__ rowcnt,
                            const float* __restrict__ rel) {
    __shared__ int stride_s;
    __shared__ int hs[B_], rs[B_];
    if (threadIdx.x == 0) {
        int all_hi_zero = 1;
        for (int i = 0; i < 99; i++)
            if (raw[2 * i + 1] != 0) { all_hi_zero = 0; break; }
        stride_s = all_hi_zero ? 2 : 1;
    }
    __syncthreads();
    int st = stride_s;
    for (int i = threadIdx.x; i < B_ * K_; i += blockDim.x)
        tb[i] = raw[(i * 3 + 1) * st];
    if (threadIdx.x < B_) {
        int b = threadIdx.x;
        int h = raw[(b * K_ * 3 + 0) * st];
        int r = raw[(b * K_ * 3 + 2) * st];
        hb[b] = h; rb[b] = r; hs[b] = h; rs[b] = r;
    }
    __syncthreads();
    int b = threadIdx.x >> 6;
    int lane = threadIdx.x & 63;
    int node = hs[b];
    int row = b * N_ + node;
    x[row * D_ + lane] = rel[(b * R_ + rs[b]) * D_ + lane];
    if (lane == 0) {
        atomicOr(&flags[row], 1 | 4);
        atomicOr(&bitset[node >> 4], 1u << (((node & 15) << 1) | b));
        int idx = atomicAdd(rowcnt, 1);
        if (idx < ROWCAP) rowlist[idx] = row;
    }
}

__global__ void scatter_kernel(const float* __restrict__ x, float* __restrict__ agg,
                               const int* __restrict__ ei, const int* __restrict__ etype,
                               const float* __restrict__ rel,
                               int* __restrict__ flags,
                               const unsigned* __restrict__ bitset,
                               int* __restrict__ rowlist, int* __restrict__ rowcnt) {
    __shared__ uint4 bs4[782];
    unsigned* bs = (unsigned*)bs4;
    const uint4* g4 = (const uint4*)bitset;
    for (int i = threadIdx.x; i < 781; i += 256) bs4[i] = g4[i];
    if (threadIdx.x == 0) bs[3124] = bitset[3124];
    const int t = blockIdx.x * 256 + threadIdx.x;
    const int4* s4 = (const int4*)ei;
    int4 u0 = s4[t];
    int v4p1 = t + SCAT_THREADS;
    bool ok1 = v4p1 < NV4;
    int4 u1 = s4[ok1 ? v4p1 : t];
    __syncthreads();
    const int lane = threadIdx.x & 63;
    const int wv4 = blockIdx.x * 256 + (threadIdx.x & ~63);
    #pragma unroll
    for (int p = 0; p < 2; p++) {
        int4 u = p ? u1 : u0;
        bool ok = p ? ok1 : true;
        int sv[4] = {u.x, u.y, u.z, u.w};
        unsigned act = 0;
        if (ok) {
            #pragma unroll
            for (int k = 0; k < 4; k++) {
                int s = sv[k];
                act |= ((bs[s >> 4] >> ((s & 15) << 1)) & 3u) << (k * 2);
            }
        }
        #pragma unroll
        for (int k = 0; k < 4; k++) {
            #pragma unroll
            for (int b = 0; b < B_; b++) {
                unsigned long long mask = __ballot((act >> (k * 2 + b)) & 1);
                while (mask) {
                    int i = __builtin_ctzll(mask);
                    mask &= mask - 1;
                    int e = (wv4 + i + p * SCAT_THREADS) * 4 + k;
                    int si = __shfl(sv[k], i, 64);
                    int di = ei[E_ + e];
                    int ti = etype[e];
                    float v = x[(b * N_ + si) * D_ + lane] * rel[(b * R_ + ti) * D_ + lane];
                    atomicAdd(&agg[(b * N_ + di) * D_ + lane], v);
                    if (lane == 0) {
                        int old = atomicOr(&flags[b * N_ + di], 2 | 4);
                        if (!(old & 4)) {
                            int idx = atomicAdd(rowcnt, 1);
                            if (idx < ROWCAP) rowlist[idx] = b * N_ + di;
                        }
                    }
                }
            }
        }
    }
}

__global__ void update_kernel(float* __restrict__ x, float* __restrict__ agg,
                              int* __restrict__ flags, unsigned* __restrict__ bitset,
                              const int* __restrict__ rowlist,
                              const int* __restrict__ rowcnt,
                              const int* __restrict__ hb, const int* __restrict__ rb,
                              const float* __restrict__ rel,
                              const float* __restrict__ W,
                              const float* __restrict__ bias,
                              const float* __restrict__ g,
                              const float* __restrict__ be) {
    const int lane = threadIdx.x & 63;
    const int cnt = min(*rowcnt, ROWCAP);
    int idx = blockIdx.x * (blockDim.x >> 6) + (threadIdx.x >> 6);
    const int nw = gridDim.x * (blockDim.x >> 6);
    for (; idx < cnt; idx += nw) {
        int row = rowlist[idx];
        int f = flags[row];
        int b = (row >= N_) ? 1 : 0;
        int node = row - b * N_;
        float a = agg[row * D_ + lane];
        if (row == b * N_ + hb[b])
            a += rel[(b * R_ + rb[b]) * D_ + lane];
        float xo = (f & 1) ? x[row * D_ + lane] : 0.0f;
        float y = bias[lane];
        #pragma unroll 8
        for (int i = 0; i < 64; i++) {
            float av = __shfl(a, i, 64);
            y += av * W[i * 64 + lane];
        }
        #pragma unroll 8
        for (int i = 0; i < 64; i++) {
            float xv = __shfl(xo, i, 64);
            y += xv * W[(64 + i) * 64 + lane];
        }
        float mu = wave_sum64(y) * (1.0f / 64.0f);
        float dlt = y - mu;
        float var = wave_sum64(dlt * dlt) * (1.0f / 64.0f);
        float upd = dlt * rsqrtf(var + 1e-5f) * g[lane] + be[lane];
        upd = fmaxf(upd, 0.0f);
        x[row * D_ + lane] = upd + xo;
        agg[row * D_ + lane] = 0.0f;
        if (lane == 0) {
            flags[row] = (f | 1) & ~2;
            atomicOr(&bitset[node >> 4], 1u << (((node & 15) << 1) | b));
        }
    }
}

__global__ void score_kernel(const float* __restrict__ x, const int* __restrict__ flags,
                             const int* __restrict__ tb, const int* __restrict__ rb,
                             const float* __restrict__ rel,
                             const float* __restrict__ w1,
                             const float* __restrict__ b1,
                             const float* __restrict__ w2,
                             const float* __restrict__ b2,
                             float* __restrict__ out) {
    int idx = blockIdx.x;
    int lane = threadIdx.x;
    int b = idx / K_;
    int t  = tb[idx];
    int r0 = rb[b];
    int row = b * N_ + t;
    float q   = rel[(b * R_ + r0) * D_ + lane];
    float hid = (flags[row] & 1) ? x[row * D_ + lane] : 0.0f;
    float acc = b1[lane];
    #pragma unroll 8
    for (int i = 0; i < 64; i++) acc += __shfl(hid, i, 64) * w1[i * 64 + lane];
    #pragma unroll 8
    for (int i = 0; i < 64; i++) acc += __shfl(q, i, 64) * w1[(64 + i) * 64 + lane];
    acc = fmaxf(acc, 0.0f);
    float s = wave_sum64(acc * w2[lane]);
    if (lane == 0) out[idx] = s + b2[0];
}

extern "C" void kernel_launch(void* const* d_in, const int* in_sizes, int n_in,
                              void* d_out, int out_size, void* d_ws, size_t ws_size,
                              hipStream_t stream) {
    const float* rel     = (const float*)d_in[0];
    const float* layer_w = (const float*)d_in[1];
    const float* layer_b = (const float*)d_in[2];
    const float* ln_g    = (const float*)d_in[3];
    const float* ln_b    = (const float*)d_in[4];
    const float* mlp_w1  = (const float*)d_in[5];
    const float* mlp_b1  = (const float*)d_in[6];
    const float* mlp_w2  = (const float*)d_in[7];
    const float* mlp_b2  = (const float*)d_in[8];
    const int* batch_raw = (const int*)d_in[9];
    const int* ei    = (const int*)d_in[10];
    const int* etype = (const int*)d_in[11];
    (void)in_sizes; (void)n_in; (void)out_size; (void)ws_size;

    char* ws = (char*)d_ws;

    FusedArgs fa;
    fa.rel = rel; fa.layer_w = layer_w; fa.layer_b = layer_b;
    fa.ln_g = ln_g; fa.ln_b = ln_b;
    fa.mlp_w1 = mlp_w1; fa.mlp_b1 = mlp_b1; fa.mlp_w2 = mlp_w2; fa.mlp_b2 = mlp_b2;
    fa.raw = batch_raw; fa.ei = ei; fa.etype = etype;
    fa.ws = ws; fa.out = (float*)d_out;
    void* kargs[] = { (void*)&fa };

    hipError_t err = hipLaunchCooperativeKernel(fused_kernel, dim3(FGRID), dim3(256),
                                                kargs, 0, stream);
    if (err != hipSuccess) {
        (void)hipGetLastError();                // clear sticky error
        // ---------- Fallback: proven R1 multi-kernel path ----------
        float* x        = (float*)(ws);
        float* agg      = (float*)(ws + 25600000);
        int* flags      = (int*)  (ws + 51200000);
        int* rowlist    = (int*)  (ws + 51600000);
        unsigned* bitset= (unsigned*)(ws + 51987488);
        int* rowcnt     = (int*)  (ws + 52000000);
        int* hb         = (int*)  (ws + 52000008);
        int* rb         = (int*)  (ws + 52000016);
        int* tb         = (int*)  (ws + 52000024);

        hipMemsetAsync(ws + 25600000, 0, 26400288, stream);
        init_kernel<<<1, 128, 0, stream>>>(batch_raw, hb, rb, tb, x, flags, bitset,
                                           rowlist, rowcnt, rel);
        for (int l = 0; l < L_; l++) {
            scatter_kernel<<<SCAT_BLOCKS, 256, 0, stream>>>(x, agg, ei, etype, rel,
                                                            flags, bitset, rowlist, rowcnt);
            update_kernel<<<256, 256, 0, stream>>>(x, agg, flags, bitset,
                                                   rowlist, rowcnt, hb, rb, rel,
                                                   layer_w + (size_t)l * 128 * 64,
                                                   layer_b + l * 64,
                                                   ln_g + l * 64,
                                                   ln_b + l * 64);
        }
        score_kernel<<<B_ * K_, 64, 0, stream>>>(x, flags, tb, rb, rel, mlp_w1, mlp_b1,
                                                 mlp_w2, mlp_b2, (float*)d_out);
    }
}

// Round 11
// 172.120 us; speedup vs baseline: 1.0541x; 1.0541x over previous
//
#include <hip/hip_runtime.h>

// Problem constants (fixed by the harness / reference setup_inputs)
#define B_ 2
#define K_ 33
#define N_ 50000
#define E_ 800000
#define R_ 200
#define D_ 64
#define L_ 3

#define ROWCAP 95000      // rowlist entries
#define NV4 200000        // E/4 int4-groups
#define SCAT_BLOCKS 391   // fallback scan grid
#define SCAT_THREADS (SCAT_BLOCKS * 256)
#define FGRID 256         // fused grid: 1 block/CU, co-resident via cooperative launch
#define FTHREADS (FGRID * 256)
#define NGRP 16           // barrier tree: 16 groups x 16 blocks
#define GSZ  16
#define READY_MAGIC 0x5F0F00D5CAFEB007ull
#define ECAP_LDS 4000     // edge records staged in LDS (32 KB); global fallback above
#define ZCHUNK 196        // ceil(50,000 flags-u64 / 256)

#define SCOPE_AG __HIP_MEMORY_SCOPE_AGENT

// ---- relaxed agent-scope (cross-XCD coherent, no cache-wide fences) ----
// R4-R10 lessons: ockl grid.sync ~45us/barrier; tree barrier ~3us; no op
// POPULATION dominates (R9: staging loads 15x down = -6us; R10: WRITE
// 26MB -> 0.7MB = +-0us). Cost = number of SERIAL grid-wide segments x
// ~2-4us coherence/straggler floor each. This round cuts segments 18->13:
// per-block cached decode (no ws hb/rb/tb), L1 probe via register
// compare (no L1 bitset), next-layer bitset built inside the update
// segment (rowlist is final there — claims only happen in scans).
__device__ inline float aldf(float* p)            { return __hip_atomic_load(p, __ATOMIC_RELAXED, SCOPE_AG); }
__device__ inline void  astf(float* p, float v)   { __hip_atomic_store(p, v, __ATOMIC_RELAXED, SCOPE_AG); }
__device__ inline int   aldi(int* p)              { return __hip_atomic_load(p, __ATOMIC_RELAXED, SCOPE_AG); }
__device__ inline void  asti(int* p, int v)       { __hip_atomic_store(p, v, __ATOMIC_RELAXED, SCOPE_AG); }
__device__ inline unsigned aldu(unsigned* p)      { return __hip_atomic_load(p, __ATOMIC_RELAXED, SCOPE_AG); }
__device__ inline void  astu(unsigned* p, unsigned v) { __hip_atomic_store(p, v, __ATOMIC_RELAXED, SCOPE_AG); }
__device__ inline unsigned long long ald64(unsigned long long* p) { return __hip_atomic_load(p, __ATOMIC_RELAXED, SCOPE_AG); }
__device__ inline void  ast64(unsigned long long* p, unsigned long long v) { __hip_atomic_store(p, v, __ATOMIC_RELAXED, SCOPE_AG); }

// Two-level tree barrier, monotonic epochs (no reset races). See R6.
__device__ inline void gridbar(unsigned* bar, unsigned epoch) {
    __syncthreads();    // per-wave vmcnt(0) drain before s_barrier = release
    if (threadIdx.x == 0) {
        const int g = (int)(blockIdx.x >> 4);
        unsigned* gcnt = bar + (1 + g) * 32;
        unsigned* ggo  = gcnt + 1;
        unsigned prev = __hip_atomic_fetch_add(gcnt, 1u, __ATOMIC_RELAXED, SCOPE_AG);
        if (prev == epoch * GSZ - 1) {              // last arriver in group
            unsigned r = __hip_atomic_fetch_add(bar, 1u, __ATOMIC_RELAXED, SCOPE_AG);
            if (r == epoch * NGRP - 1) {            // last group -> release everyone
                #pragma unroll
                for (int i = 0; i < NGRP; ++i)
                    astu(bar + (1 + i) * 32 + 1, epoch);
            }
        }
        while (aldu(ggo) < epoch) __builtin_amdgcn_s_sleep(1);
    }
    __syncthreads();
}

__device__ inline float wave_sum64(float v) {
    for (int m = 32; m; m >>= 1) v += __shfl_xor(v, m, 64);
    return v;
}

// flags bits: 1 = x-active, 4 = rowlist claim.
// Workspace layout (proven ws_size >= 52,000,288):
//   x       @ 0           25,600,000  (reads gated by flags bit0)
//   elist   @ 25,600,000  25,600,000  (3.2M u64 records; cap >= E*B worst case)
//   flags   @ 51,200,000     400,000  (zeroed, balanced)
//   rowlist @ 51,600,000     380,000  (ROWCAP entries, ends 51,980,000)
//   ecnt[3] @ 51,980,016          12
//   bar     @ 51,980,032       2,176  (17 x 128 B tree-barrier lines)
//   ready   @ 51,987,480  (u64 magic)
//   rowcnt  @ 52,000,000

struct FusedArgs {
    const float *rel, *layer_w, *layer_b, *ln_g, *ln_b;
    const float *mlp_w1, *mlp_b1, *mlp_w2, *mlp_b2;
    const int *raw, *ei, *etype;
    char* ws;
    float* out;
};

__global__ __launch_bounds__(256) void fused_kernel(FusedArgs A) {
    char* ws = A.ws;
    float*    x       = (float*)(ws);
    unsigned long long* elist = (unsigned long long*)(ws + 25600000);
    int*      flags   = (int*)(ws + 51200000);
    int*      rowlist = (int*)(ws + 51600000);
    int*      ecnt    = (int*)(ws + 51980016);
    unsigned* bar     = (unsigned*)(ws + 51980032);
    unsigned long long* ready = (unsigned long long*)(ws + 51987480);
    int*      rowcnt  = (int*)(ws + 52000000);
    unsigned long long* fzu = (unsigned long long*)flags;  // 50,000 u64

    const int tid  = threadIdx.x;
    const int lane = tid & 63;
    const int gtid = blockIdx.x * 256 + tid;
    const int gw   = gtid >> 6;                 // global wave id, 0..1023

    __shared__ unsigned long long bsll[1564];   // 12,512 B LDS src-activity bitset
    __shared__ unsigned long long tact[1564];   // 12,512 B target-dst bitset (L3 filter)
    __shared__ unsigned long long elds[ECAP_LDS]; // 32,000 B staged edge records
    __shared__ int tbl_s[B_ * K_];              // decoded t-indices (66)
    __shared__ int hbs[B_], rbs[B_];
    __shared__ int nz_s, cnt_s, ce_s;

    // ---- per-block decode of batch from A.raw (cached, read-only; no ws) ----
    if (tid == 0) nz_s = 0;
    for (int i = tid; i < 1564; i += 256) tact[i] = 0ull;
    __syncthreads();
    // int64-vs-int32 detect: any hi-word nonzero -> int32 (stride 1)
    if (tid < 99 && A.raw[2 * tid + 1] != 0) atomicOr(&nz_s, 1);
    __syncthreads();
    const int st = nz_s ? 1 : 2;
    if (tid < B_ * K_) tbl_s[tid] = A.raw[(tid * 3 + 1) * st];
    if (tid < B_) {
        hbs[tid] = A.raw[(tid * K_ * 3 + 0) * st];
        rbs[tid] = A.raw[(tid * K_ * 3 + 2) * st];
    }
    __syncthreads();
    if (tid < B_ * K_) {                        // target-dst bitset (L3 filter)
        int b = tid / K_;
        int t = tbl_s[tid];
        atomicOr(&((unsigned*)tact)[t >> 4], 1u << (((t & 15) << 1) | b));
    }
    const int hb0 = hbs[0], hb1 = hbs[1], rb0 = rbs[0], rb1 = rbs[1];

    // ---- barrier bootstrap over poisoned ws (block0 publishes magic) ----
    if (blockIdx.x == 0) {
        for (int i = tid; i < 17 * 32; i += 256) astu(&bar[i], 0u);
        if (tid == 0) {
            asti(rowcnt, 0);
            asti(&ecnt[0], 0); asti(&ecnt[1], 0); asti(&ecnt[2], 0);
        }
        __syncthreads();                        // drains all zero-stores
        if (tid == 0) ast64(ready, READY_MAGIC);
    } else if (tid == 0) {
        while (ald64(ready) != READY_MAGIC) __builtin_amdgcn_s_sleep(1);
    }

    // ---------- P0: balanced flags zero + x seed (block 0) ----------
    {
        int lo = blockIdx.x * ZCHUNK;
        int hi = lo + ZCHUNK; if (hi > 50000) hi = 50000;
        for (int i = lo + tid; i < hi; i += 256) ast64(&fzu[i], 0ull);
    }
    if (blockIdx.x == 0 && tid < 128) {         // x seed (flags claim deferred)
        int b = tid >> 6;
        int h = b ? hb1 : hb0;
        int r = b ? rb1 : rb0;
        astf(&x[(b * N_ + h) * D_ + lane], A.rel[(b * R_ + r) * D_ + lane]);
    }
    unsigned bark = 0;
    gridbar(bar, ++bark);

    // ---------- layers (unrolled: l-branches fold) ----------
    #pragma unroll
    for (int l = 0; l < L_; ++l) {
        const float* W    = A.layer_w + (size_t)l * 128 * 64;
        const float* bias = A.layer_b + l * 64;
        const float* gam  = A.ln_g + l * 64;
        const float* bet  = A.ln_b + l * 64;

        // Deferred seed claims (idempotent vs concurrent scan claims; both
        // RMWs complete before the post-scan barrier, so update sees 1|4).
        if (l == 0 && blockIdx.x == 0 && tid < B_) {
            int row = tid * N_ + (tid ? hb1 : hb0);
            int old = atomicOr(&flags[row], 1 | 4);
            if (!(old & 4)) {
                int idx = atomicAdd(rowcnt, 1);
                if (idx < ROWCAP) asti(&rowlist[idx], row);
            }
        }

        // ---- scan: O(E) cached probe; actives -> packed edge-list append ----
        // l==0: probe = register compare vs hb0/hb1 (no bitset at all).
        // l>=1: probe = LDS bitset built in the previous update segment.
        // l==2: dst must also be in target set; no claims (no worklist after).
        {
            const unsigned* bs = (const unsigned*)bsll;
            const unsigned* tw = (const unsigned*)tact;
            for (int i = gtid; i < NV4; i += FTHREADS) {
                int4 u = ((const int4*)A.ei)[i];        // ei read-only: plain cached
                int sv[4] = {u.x, u.y, u.z, u.w};
                int dv[4] = {0, 0, 0, 0};
                unsigned act = 0;
                #pragma unroll
                for (int k = 0; k < 4; ++k) {
                    int s = sv[k];
                    if (l == 0) {
                        act |= (s == hb0 ? 1u : 0u) << (k * 2);
                        act |= (s == hb1 ? 1u : 0u) << (k * 2 + 1);
                    } else {
                        act |= ((bs[s >> 4] >> ((s & 15) << 1)) & 3u) << (k * 2);
                    }
                }
                if (l == 2) {
                    int4 ud = ((const int4*)(A.ei + E_))[i];
                    dv[0] = ud.x; dv[1] = ud.y; dv[2] = ud.z; dv[3] = ud.w;
                    unsigned tm = 0;
                    #pragma unroll
                    for (int k = 0; k < 4; ++k) {
                        int d = dv[k];
                        tm |= ((tw[d >> 4] >> ((d & 15) << 1)) & 3u) << (k * 2);
                    }
                    act &= tm;
                }
                #pragma unroll
                for (int k = 0; k < 4; ++k) {
                    #pragma unroll
                    for (int b = 0; b < B_; ++b) {
                        bool mine = (act >> (k * 2 + b)) & 1;
                        unsigned long long mask = __ballot(mine);
                        if (!mask) continue;
                        int leader = __builtin_ctzll(mask);
                        int base = 0;
                        if (lane == leader)
                            base = atomicAdd(&ecnt[l], (int)__popcll(mask));
                        base = __shfl(base, leader, 64);
                        if (mine) {
                            int rank = (int)__popcll(mask & ((1ull << lane) - 1ull));
                            int e  = i * 4 + k;                 // own edge
                            int si = sv[k];
                            int di = (l == 2) ? dv[k] : A.ei[E_ + e];
                            int ti = A.etype[e];
                            unsigned long long rec =
                                (unsigned long long)(unsigned)di
                              | ((unsigned long long)(unsigned)si << 16)
                              | ((unsigned long long)(unsigned)ti << 32)
                              | ((unsigned long long)(unsigned)b  << 40);
                            ast64(&elist[base + rank], rec);
                            if (l < 2) {
                                int drow = b * N_ + di;
                                int old = atomicOr(&flags[drow], 4);
                                if (!(old & 4)) {
                                    int idx = atomicAdd(rowcnt, 1);
                                    if (idx < ROWCAP) asti(&rowlist[idx], drow);
                                }
                            }
                        }
                    }
                }
            }
        }
        gridbar(bar, ++bark);

        // ---- stage edge list + build NEXT layer's bitset + update ----
        // rowlist/ecnt are final here (claims happen only in scans), so the
        // l+1 bitset build lives inside this segment (no standalone phase).
        if (tid == 0) {
            ce_s = aldi(&ecnt[l]);
            cnt_s = min(aldi(rowcnt), ROWCAP);
        }
        if (l < 2) for (int i = tid; i < 1564; i += 256) bsll[i] = 0ull;
        __syncthreads();
        const int ce = ce_s;
        const int cnt = cnt_s;
        const bool inlds = (ce <= ECAP_LDS);
        if (inlds) for (int j = tid; j < ce; j += 256) elds[j] = ald64(&elist[j]);
        if (l < 2) {
            unsigned* bsw = (unsigned*)bsll;
            int pairs = (cnt + 1) >> 1;
            for (int i = tid; i < pairs; i += 256) {
                unsigned long long v = ald64((unsigned long long*)&rowlist[2 * i]);
                int r0 = (int)(unsigned)v;
                int c0 = (r0 >= N_) ? 1 : 0, n0 = r0 - c0 * N_;
                atomicOr(&bsw[n0 >> 4], 1u << (((n0 & 15) << 1) | c0));
                if (2 * i + 1 < cnt) {
                    int r1 = (int)(v >> 32);
                    int c1 = (r1 >= N_) ? 1 : 0, n1 = r1 - c1 * N_;
                    atomicOr(&bsw[n1 >> 4], 1u << (((n1 & 15) << 1) | c1));
                }
            }
        }
        __syncthreads();

        if (l < 2) {
            // ---- update: gather from edge list; [a, x] @ W; LN; relu; x += ----
            for (int idx = gw; idx < cnt; idx += FTHREADS >> 6) {
                int row = aldi(&rowlist[idx]);
                int f = aldi(&flags[row]);
                int b = (row >= N_) ? 1 : 0;
                int node = row - b * N_;
                float a = 0.0f;
                for (int j0 = 0; j0 < ce; j0 += 64) {
                    int jj = j0 + lane;
                    unsigned long long rec = 0;
                    bool valid = jj < ce;
                    if (valid) rec = inlds ? elds[jj] : ald64(&elist[jj]);
                    bool match = valid && ((int)(rec & 0xFFFFu) == node)
                                       && ((int)((rec >> 40) & 1u) == b);
                    unsigned long long mask = __ballot(match);
                    while (mask) {
                        int j = __builtin_ctzll(mask);
                        mask &= mask - 1;
                        unsigned long long rj = __shfl(rec, j, 64);
                        int si = (int)((rj >> 16) & 0xFFFFu);
                        int ti = (int)((rj >> 32) & 0xFFu);
                        a += aldf(&x[(b * N_ + si) * D_ + lane])
                           * A.rel[(b * R_ + ti) * D_ + lane];
                    }
                }
                if (node == (b ? hb1 : hb0))            // boundary (= query)
                    a += A.rel[(b * R_ + (b ? rb1 : rb0)) * D_ + lane];
                float xo = (f & 1) ? aldf(&x[row * D_ + lane]) : 0.0f;
                float y = bias[lane];
                #pragma unroll 8
                for (int i = 0; i < 64; ++i)
                    y += __shfl(a, i, 64) * W[i * 64 + lane];
                #pragma unroll 8
                for (int i = 0; i < 64; ++i)
                    y += __shfl(xo, i, 64) * W[(64 + i) * 64 + lane];
                float mu = wave_sum64(y) * (1.0f / 64.0f);
                float dlt = y - mu;
                float var = wave_sum64(dlt * dlt) * (1.0f / 64.0f);
                float upd = fmaxf(dlt * rsqrtf(var + 1e-5f) * gam[lane] + bet[lane], 0.0f);
                astf(&x[row * D_ + lane], upd + xo);
                if (lane == 0)
                    asti(&flags[row], f | 1);           // x-active
            }
            gridbar(bar, ++bark);
        } else {
            // ---- L3 update + score fused, targets only, no barrier after ----
            if (gw < B_ * K_) {
                int b = gw / K_;
                int t = tbl_s[gw];
                int row = b * N_ + t;
                int f = aldi(&flags[row]);
                float a = 0.0f;
                for (int j0 = 0; j0 < ce; j0 += 64) {
                    int jj = j0 + lane;
                    unsigned long long rec = 0;
                    bool valid = jj < ce;
                    if (valid) rec = inlds ? elds[jj] : ald64(&elist[jj]);
                    bool match = valid && ((int)(rec & 0xFFFFu) == t)
                                       && ((int)((rec >> 40) & 1u) == b);
                    unsigned long long mask = __ballot(match);
                    while (mask) {
                        int j = __builtin_ctzll(mask);
                        mask &= mask - 1;
                        unsigned long long rj = __shfl(rec, j, 64);
                        int si = (int)((rj >> 16) & 0xFFFFu);
                        int ti = (int)((rj >> 32) & 0xFFu);
                        a += aldf(&x[(b * N_ + si) * D_ + lane])
                           * A.rel[(b * R_ + ti) * D_ + lane];
                    }
                }
                if (t == (b ? hb1 : hb0))               // boundary (= query)
                    a += A.rel[(b * R_ + (b ? rb1 : rb0)) * D_ + lane];
                float xo = (f & 1) ? aldf(&x[row * D_ + lane]) : 0.0f;
                float y = bias[lane];
                #pragma unroll 8
                for (int i = 0; i < 64; ++i)
                    y += __shfl(a, i, 64) * W[i * 64 + lane];
                #pragma unroll 8
                for (int i = 0; i < 64; ++i)
                    y += __shfl(xo, i, 64) * W[(64 + i) * 64 + lane];
                float mu = wave_sum64(y) * (1.0f / 64.0f);
                float dlt = y - mu;
                float var = wave_sum64(dlt * dlt) * (1.0f / 64.0f);
                float upd = fmaxf(dlt * rsqrtf(var + 1e-5f) * gam[lane] + bet[lane], 0.0f);
                float res = upd + xo;                   // x3[row], in-register
                // inline final MLP score
                float q = A.rel[(b * R_ + (b ? rb1 : rb0)) * D_ + lane];
                float acc = A.mlp_b1[lane];
                #pragma unroll 8
                for (int i = 0; i < 64; ++i)
                    acc += __shfl(res, i, 64) * A.mlp_w1[i * 64 + lane];
                #pragma unroll 8
                for (int i = 0; i < 64; ++i)
                    acc += __shfl(q, i, 64) * A.mlp_w1[(64 + i) * 64 + lane];
                acc = fmaxf(acc, 0.0f);
                float s = wave_sum64(acc * A.mlp_w2[lane]);
                if (lane == 0) A.out[gw] = s + A.mlp_b2[0];
            }
        }
    }

    // Reset magic so a future run never sees stale MAGIC with un-zeroed
    // counters (hang hazard if a poison pass is ever skipped).
    if (blockIdx.x == 0 && tid == 0) ast64(ready, 0ull);
}

// =====================================================================
// Fallback path: proven R1 multi-kernel pipeline (launch-error only)
// =====================================================================
__global__ void init_kernel(const int* __restrict__ raw,
                            int* __restrict__ hb, int* __restrict__ rb,
                            int* __restrict__ tb,
                            float* __restrict__ x, int* __restrict__ flags,
                            unsigned* __restrict__ bitset,
                            int* __restrict__ rowlist, int* __restrict__ rowcnt,
                            const float* __restrict__ rel) {
    __shared__ int stride_s;
    __shared__ int hs[B_], rs[B_];
    if (threadIdx.x == 0) {
        int all_hi_zero = 1;
        for (int i = 0; i < 99; i++)
            if (raw[2 * i + 1] != 0) { all_hi_zero = 0; break; }
        stride_s = all_hi_zero ? 2 : 1;
    }
    __syncthreads();
    int st = stride_s;
    for (int i = threadIdx.x; i < B_ * K_; i += blockDim.x)
        tb[i] = raw[(i * 3 + 1) * st];
    if (threadIdx.x < B_) {
        int b = threadIdx.x;
        int h = raw[(b * K_ * 3 + 0) * st];
        int r = raw[(b * K_ * 3 + 2) * st];
        hb[b] = h; rb[b] = r; hs[b] = h; rs[b] = r;
    }
    __syncthreads();
    int b = threadIdx.x >> 6;
    int lane = threadIdx.x & 63;
    int node = hs[b];
    int row = b * N_ + node;
    x[row * D_ + lane] = rel[(b * R_ + rs[b]) * D_ + lane];
    if (lane == 0) {
        atomicOr(&flags[row], 1 | 4);
        atomicOr(&bitset[node >> 4], 1u << (((node & 15) << 1) | b));
        int idx = atomicAdd(rowcnt, 1);
        if (idx < ROWCAP) rowlist[idx] = row;
    }
}

__global__ void scatter_kernel(const float* __restrict__ x, float* __restrict__ agg,
                               const int* __restrict__ ei, const int* __restrict__ etype,
                               const float* __restrict__ rel,
                               int* __restrict__ flags,
                               const unsigned* __restrict__ bitset,
                               int* __restrict__ rowlist, int* __restrict__ rowcnt) {
    __shared__ uint4 bs4[782];
    unsigned* bs = (unsigned*)bs4;
    const uint4* g4 = (const uint4*)bitset;
    for (int i = threadIdx.x; i < 781; i += 256) bs4[i] = g4[i];
    if (threadIdx.x == 0) bs[3124] = bitset[3124];
    const int t = blockIdx.x * 256 + threadIdx.x;
    const int4* s4 = (const int4*)ei;
    int4 u0 = s4[t];
    int v4p1 = t + SCAT_THREADS;
    bool ok1 = v4p1 < NV4;
    int4 u1 = s4[ok1 ? v4p1 : t];
    __syncthreads();
    const int lane = threadIdx.x & 63;
    const int wv4 = blockIdx.x * 256 + (threadIdx.x & ~63);
    #pragma unroll
    for (int p = 0; p < 2; p++) {
        int4 u = p ? u1 : u0;
        bool ok = p ? ok1 : true;
        int sv[4] = {u.x, u.y, u.z, u.w};
        unsigned act = 0;
        if (ok) {
            #pragma unroll
            for (int k = 0; k < 4; k++) {
                int s = sv[k];
                act |= ((bs[s >> 4] >> ((s & 15) << 1)) & 3u) << (k * 2);
            }
        }
        #pragma unroll
        for (int k = 0; k < 4; k++) {
            #pragma unroll
            for (int b = 0; b < B_; b++) {
                unsigned long long mask = __ballot((act >> (k * 2 + b)) & 1);
                while (mask) {
                    int i = __builtin_ctzll(mask);
                    mask &= mask - 1;
                    int e = (wv4 + i + p * SCAT_THREADS) * 4 + k;
                    int si = __shfl(sv[k], i, 64);
                    int di = ei[E_ + e];
                    int ti = etype[e];
                    float v = x[(b * N_ + si) * D_ + lane] * rel[(b * R_ + ti) * D_ + lane];
                    atomicAdd(&agg[(b * N_ + di) * D_ + lane], v);
                    if (lane == 0) {
                        int old = atomicOr(&flags[b * N_ + di], 2 | 4);
                        if (!(old & 4)) {
                            int idx = atomicAdd(rowcnt, 1);
                            if (idx < ROWCAP) rowlist[idx] = b * N_ + di;
                        }
                    }
                }
            }
        }
    }
}

__global__ void update_kernel(float* __restrict__ x, float* __restrict__ agg,
                              int* __restrict__ flags, unsigned* __restrict__ bitset,
                              const int* __restrict__ rowlist,
                              const int* __restrict__ rowcnt,
                              const int* __restrict__ hb, const int* __restrict__ rb,
                              const float* __restrict__ rel,
                              const float* __restrict__ W,
                              const float* __restrict__ bias,
                              const float* __restrict__ g,
                              const float* __restrict__ be) {
    const int lane = threadIdx.x & 63;
    const int cnt = min(*rowcnt, ROWCAP);
    int idx = blockIdx.x * (blockDim.x >> 6) + (threadIdx.x >> 6);
    const int nw = gridDim.x * (blockDim.x >> 6);
    for (; idx < cnt; idx += nw) {
        int row = rowlist[idx];
        int f = flags[row];
        int b = (row >= N_) ? 1 : 0;
        int node = row - b * N_;
        float a = agg[row * D_ + lane];
        if (row == b * N_ + hb[b])
            a += rel[(b * R_ + rb[b]) * D_ + lane];
        float xo = (f & 1) ? x[row * D_ + lane] : 0.0f;
        float y = bias[lane];
        #pragma unroll 8
        for (int i = 0; i < 64; i++) {
            float av = __shfl(a, i, 64);
            y += av * W[i * 64 + lane];
        }
        #pragma unroll 8
        for (int i = 0; i < 64; i++) {
            float xv = __shfl(xo, i, 64);
            y += xv * W[(64 + i) * 64 + lane];
        }
        float mu = wave_sum64(y) * (1.0f / 64.0f);
        float dlt = y - mu;
        float var = wave_sum64(dlt * dlt) * (1.0f / 64.0f);
        float upd = dlt * rsqrtf(var + 1e-5f) * g[lane] + be[lane];
        upd = fmaxf(upd, 0.0f);
        x[row * D_ + lane] = upd + xo;
        agg[row * D_ + lane] = 0.0f;
        if (lane == 0) {
            flags[row] = (f | 1) & ~2;
            atomicOr(&bitset[node >> 4], 1u << (((node & 15) << 1) | b));
        }
    }
}

__global__ void score_kernel(const float* __restrict__ x, const int* __restrict__ flags,
                             const int* __restrict__ tb, const int* __restrict__ rb,
                             const float* __restrict__ rel,
                             const float* __restrict__ w1,
                             const float* __restrict__ b1,
                             const float* __restrict__ w2,
                             const float* __restrict__ b2,
                             float* __restrict__ out) {
    int idx = blockIdx.x;
    int lane = threadIdx.x;
    int b = idx / K_;
    int t  = tb[idx];
    int r0 = rb[b];
    int row = b * N_ + t;
    float q   = rel[(b * R_ + r0) * D_ + lane];
    float hid = (flags[row] & 1) ? x[row * D_ + lane] : 0.0f;
    float acc = b1[lane];
    #pragma unroll 8
    for (int i = 0; i < 64; i++) acc += __shfl(hid, i, 64) * w1[i * 64 + lane];
    #pragma unroll 8
    for (int i = 0; i < 64; i++) acc += __shfl(q, i, 64) * w1[(64 + i) * 64 + lane];
    acc = fmaxf(acc, 0.0f);
    float s = wave_sum64(acc * w2[lane]);
    if (lane == 0) out[idx] = s + b2[0];
}

extern "C" void kernel_launch(void* const* d_in, const int* in_sizes, int n_in,
                              void* d_out, int out_size, void* d_ws, size_t ws_size,
                              hipStream_t stream) {
    const float* rel     = (const float*)d_in[0];
    const float* layer_w = (const float*)d_in[1];
    const float* layer_b = (const float*)d_in[2];
    const float* ln_g    = (const float*)d_in[3];
    const float* ln_b    = (const float*)d_in[4];
    const float* mlp_w1  = (const float*)d_in[5];
    const float* mlp_b1  = (const float*)d_in[6];
    const float* mlp_w2  = (const float*)d_in[7];
    const float* mlp_b2  = (const float*)d_in[8];
    const int* batch_raw = (const int*)d_in[9];
    const int* ei    = (const int*)d_in[10];
    const int* etype = (const int*)d_in[11];
    (void)in_sizes; (void)n_in; (void)out_size; (void)ws_size;

    char* ws = (char*)d_ws;

    FusedArgs fa;
    fa.rel = rel; fa.layer_w = layer_w; fa.layer_b = layer_b;
    fa.ln_g = ln_g; fa.ln_b = ln_b;
    fa.mlp_w1 = mlp_w1; fa.mlp_b1 = mlp_b1; fa.mlp_w2 = mlp_w2; fa.mlp_b2 = mlp_b2;
    fa.raw = batch_raw; fa.ei = ei; fa.etype = etype;
    fa.ws = ws; fa.out = (float*)d_out;
    void* kargs[] = { (void*)&fa };

    hipError_t err = hipLaunchCooperativeKernel(fused_kernel, dim3(FGRID), dim3(256),
                                                kargs, 0, stream);
    if (err != hipSuccess) {
        (void)hipGetLastError();                // clear sticky error
        // ---------- Fallback: proven R1 multi-kernel path ----------
        float* x        = (float*)(ws);
        float* agg      = (float*)(ws + 25600000);
        int* flags      = (int*)  (ws + 51200000);
        int* rowlist    = (int*)  (ws + 51600000);
        unsigned* bitset= (unsigned*)(ws + 51987488);
        int* rowcnt     = (int*)  (ws + 52000000);
        int* hb         = (int*)  (ws + 52000008);
        int* rb         = (int*)  (ws + 52000016);
        int* tb         = (int*)  (ws + 52000024);

        hipMemsetAsync(ws + 25600000, 0, 26400288, stream);
        init_kernel<<<1, 128, 0, stream>>>(batch_raw, hb, rb, tb, x, flags, bitset,
                                           rowlist, rowcnt, rel);
        for (int l = 0; l < L_; l++) {
            scatter_kernel<<<SCAT_BLOCKS, 256, 0, stream>>>(x, agg, ei, etype, rel,
                                                            flags, bitset, rowlist, rowcnt);
            update_kernel<<<256, 256, 0, stream>>>(x, agg, flags, bitset,
                                                   rowlist, rowcnt, hb, rb, rel,
                                                   layer_w + (size_t)l * 128 * 64,
                                                   layer_b + l * 64,
                                                   ln_g + l * 64,
                                                   ln_b + l * 64);
        }
        score_kernel<<<B_ * K_, 64, 0, stream>>>(x, flags, tb, rb, rel, mlp_w1, mlp_b1,
                                                 mlp_w2, mlp_b2, (float*)d_out);
    }
}